// Round 4
// baseline (1315.164 us; speedup 1.0000x reference)
//
#include <hip/hip_runtime.h>
#include <hip/hip_bf16.h>
#include <stdint.h>

// MultilayerPCN: bf16-MFMA, cooperative 256x128 block tile (BK=32), split-K
// across blocks, counted-vmcnt barrier pipeline + separate fused epilogue.
// NODES = [2048, 4096, 8192], B = 256, n_iters = 8, LAMB = 0.5.
//
// r3 post-mortem: runtime ~= issued_DMA_bytes / (resident_blocks x 23 GB/s).
// Wave-private staging (r3) paid B 4x per block -> 640 MB/phase. This version:
// 4 waves cooperatively stage a shared A[256][32] + B[128][32] chunk (each wave
// 6 global_load_lds of its quarter), wave computes a 64x128 slice (4x8 frags).
// Issued bytes/phase: 246 MB. Pipeline: 3 LDS buffers (72 KB -> 2 blocks/CU),
// vmcnt(12) counted (never drained mid-loop), 2 raw s_barriers per chunk with
// sched_barrier(0) fences. LDS rows stay 64 B (r3's proven bank-floor layout).
// fp32 partials -> workspace; epilogue kernel sums kq planes + fused update.
// Runtime ws_size guard picks ks config (640-block uniform grid needs 64 MB
// CpA; falls back to 384-block config if workspace is tight).

typedef short short8x __attribute__((ext_vector_type(8)));
typedef float float4x __attribute__((ext_vector_type(4)));
typedef unsigned short u16;
typedef u16 u16x8 __attribute__((ext_vector_type(8)));

static constexpr float LOSS_SCALE = 100.0f / 256.0f;

__device__ __forceinline__ u16 f2b(float x) {
    union { float f; uint32_t u; } v{x};
    uint32_t b = v.u + 0x7fffu + ((v.u >> 16) & 1u);
    return (u16)(b >> 16);
}

__device__ __forceinline__ float signf_(float x) {
    return (x > 0.f) ? 1.f : ((x < 0.f) ? -1.f : 0.f);
}

__device__ __forceinline__ void gload_lds16(const void* g, void* lds) {
    __builtin_amdgcn_global_load_lds(
        (const __attribute__((address_space(1))) void*)g,
        (__attribute__((address_space(3))) void*)lds, 16, 0, 0);
}

// ---------------- init / cast kernels ----------------
__global__ void k_zero(float* p, int n) {
    int i = blockIdx.x * blockDim.x + threadIdx.x;
    if (i < n) p[i] = 0.f;
}

// one pass: outN = bf16(in) (R x C), outT = bf16(in^T) (C x R)
// 64x64 tiles: reads 256B/row-wave, transpose writes 128B segments.
__global__ __launch_bounds__(256) void k_cast_both(
    const float* __restrict__ in, u16* __restrict__ outN, u16* __restrict__ outT,
    int R, int C) {
    __shared__ float tile[64][65];
    int x = blockIdx.x * 64 + threadIdx.x;   // threadIdx.x in 0..63
#pragma unroll
    for (int k = 0; k < 64; k += 4) {
        int y = blockIdx.y * 64 + threadIdx.y + k;
        float v = in[(size_t)y * C + x];
        tile[threadIdx.y + k][threadIdx.x] = v;
        outN[(size_t)y * C + x] = f2b(v);
    }
    __syncthreads();
    int ox = blockIdx.y * 64 + threadIdx.x;
#pragma unroll
    for (int k = 0; k < 64; k += 4) {
        int oy = blockIdx.x * 64 + threadIdx.y + k;
        outT[(size_t)oy * R + ox] = f2b(tile[threadIdx.x][threadIdx.y + k]);
    }
}

__global__ void k_fill_v0(float* __restrict__ v0, const float* __restrict__ memory,
                          int n, int mask) {
    int i = blockIdx.x * blockDim.x + threadIdx.x;
    if (i < n) v0[i] = memory[i & mask];
}

__global__ void k_tanh(float* __restrict__ dst, const float* __restrict__ src, int n) {
    int i = blockIdx.x * blockDim.x + threadIdx.x;
    if (i < n) dst[i] = tanhf(src[i]);
}

__global__ void k_rowdot(const float* __restrict__ x, const float* __restrict__ W,
                         float* __restrict__ out, int K) {
    int i = blockIdx.x;
    const float4* w = (const float4*)(W + (size_t)i * K);
    const float4* xv = (const float4*)x;
    float s = 0.f;
    for (int j = threadIdx.x; j < (K >> 2); j += 256) {
        float4 a = xv[j], b = w[j];
        s += a.x * b.x + a.y * b.y + a.z * b.z + a.w * b.w;
    }
    __shared__ float red[256];
    red[threadIdx.x] = s;
    __syncthreads();
    for (int st = 128; st > 0; st >>= 1) {
        if (threadIdx.x < st) red[threadIdx.x] += red[threadIdx.x + st];
        __syncthreads();
    }
    if (threadIdx.x == 0) out[i] = red[0];
}

__global__ void k_bcast_v1_e1(float* __restrict__ v1, float* __restrict__ e1,
                              u16* __restrict__ e1b,
                              const float* __restrict__ r1, int n, int mask) {
    int i = blockIdx.x * blockDim.x + threadIdx.x;
    if (i < n) { v1[i] = r1[i & mask]; e1[i] = 0.f; e1b[i] = 0; }
}

__global__ void k_e2_init(u16* __restrict__ e2b, const float* __restrict__ inp,
                          const float* __restrict__ r2, int n, int mask) {
    int i = blockIdx.x * blockDim.x + threadIdx.x;
    if (i < n) e2b[i] = f2b(inp[i] - r2[i & mask]);
}

// ---------------- cooperative 256x128 split-K partial GEMM ----------------
struct GGR {
    const u16* A;       // [256, K] bf16 row-major
    const u16* Bt;      // [N, K]  bf16 row-major (B transposed)
    float* Cp;          // fp32 partials [ks][256][N]
    int N, K, nCol, ks; // nCol = N/128; blocks = nCol*ks
};

__device__ void gemm_part(const GGR& g, int bx, u16* stage) {
    const int tid = threadIdx.x;
    const int w = tid >> 6, l = tid & 63;
    const int lm = l & 15, lq = l >> 4;
    const int cb = bx / g.ks, kq = bx - cb * g.ks;
    const int K = g.K;
    const int Ksl = K / g.ks;        // >= 512, multiple of 32
    const int nCh = Ksl >> 5;        // chunks of 32 K-elements (>= 16)

    // chunk buffer bf at stage + bf*12288 u16 (24 KB):
    //   A [256][32] u16 at +0 (16 KB), B [128][32] u16 at +8192 (8 KB)
    // wave w stages A rows w*64..+63 (4 issues) and B rows w*32..+31 (2 issues).
    const u16* aSrc = g.A + (size_t)(w * 64 + (l >> 2)) * K + kq * Ksl + (l & 3) * 8;
    const u16* bSrc = g.Bt + (size_t)(cb * 128 + w * 32 + (l >> 2)) * K + kq * Ksl + (l & 3) * 8;
    const size_t rStep = (size_t)16 * K;   // 16 rows per staging issue

    int aoff[4], boff[8];
#pragma unroll
    for (int i = 0; i < 4; ++i) aoff[i] = w * 2048 + i * 512 + lm * 32 + lq * 8;
#pragma unroll
    for (int j = 0; j < 8; ++j) boff[j] = 8192 + j * 512 + lm * 32 + lq * 8;

    float4x acc[4][8];
#pragma unroll
    for (int i = 0; i < 4; ++i)
#pragma unroll
        for (int j = 0; j < 8; ++j) acc[i][j] = (float4x)0.f;

#define STAGE(c, bf) { \
    u16* ad = stage + (bf) * 12288 + w * 2048; \
    u16* bd = stage + (bf) * 12288 + 8192 + w * 1024; \
    const u16* as = aSrc + (c) * 32; \
    const u16* bs = bSrc + (c) * 32; \
    gload_lds16(as, ad);                  gload_lds16(as + rStep, ad + 512); \
    gload_lds16(as + 2 * rStep, ad + 1024); gload_lds16(as + 3 * rStep, ad + 1536); \
    gload_lds16(bs, bd);                  gload_lds16(bs + rStep, bd + 512); }

#define COMPUTE(bf) { \
    u16* ab = stage + (bf) * 12288; \
    short8x a[4], bb[8]; \
    _Pragma("unroll") for (int i = 0; i < 4; ++i) a[i] = *(const short8x*)(ab + aoff[i]); \
    _Pragma("unroll") for (int j = 0; j < 8; ++j) bb[j] = *(const short8x*)(ab + boff[j]); \
    _Pragma("unroll") for (int i = 0; i < 4; ++i) \
    _Pragma("unroll") for (int j = 0; j < 8; ++j) \
        acc[i][j] = __builtin_amdgcn_mfma_f32_16x16x32_bf16(a[i], bb[j], acc[i][j], 0, 0, 0); }

    STAGE(0, 0);
    STAGE(1, 1);
    int bf = 0, sf = 2;
    for (int c = 0; c < nCh; ++c) {
        __builtin_amdgcn_sched_barrier(0);
        if (c + 2 < nCh) { STAGE(c + 2, sf); }
        __builtin_amdgcn_sched_barrier(0);
        // wait for own chunk-c loads; keep later chunks in flight (counted vmcnt)
        if (c + 2 < nCh)      __builtin_amdgcn_s_waitcnt(0x0F7C);  // vmcnt(12)
        else if (c + 1 < nCh) __builtin_amdgcn_s_waitcnt(0x0F76);  // vmcnt(6)
        else                  __builtin_amdgcn_s_waitcnt(0x0F70);  // vmcnt(0)
        __builtin_amdgcn_sched_barrier(0);
        __builtin_amdgcn_s_barrier();      // chunk c fully in LDS (all waves)
        __builtin_amdgcn_sched_barrier(0);
        COMPUTE(bf);
        __builtin_amdgcn_sched_barrier(0);
        __builtin_amdgcn_s_barrier();      // all waves done reading buf bf
        bf = (bf == 2) ? 0 : bf + 1;
        sf = (sf == 2) ? 0 : sf + 1;
    }
#undef STAGE
#undef COMPUTE

    // store fp32 partial: frag (i,j) reg r -> row = w*64 + i*16 + lq*4 + r,
    // col = cb*128 + j*16 + lm   [C/D layout, m89-verified]
    float* cp = g.Cp + ((size_t)kq * 256 + w * 64) * g.N + (size_t)cb * 128;
#pragma unroll
    for (int i = 0; i < 4; ++i)
#pragma unroll
        for (int j = 0; j < 8; ++j)
#pragma unroll
            for (int r = 0; r < 4; ++r)
                cp[(size_t)(i * 16 + lq * 4 + r) * g.N + j * 16 + lm] = acc[i][j][r];
}

__global__ __launch_bounds__(256, 2) void pcn_gemm(GGR ga, GGR gb, int nA) {
    __shared__ u16 stage[36864];   // 3 x 24 KB = 72 KB -> 2 blocks/CU
    int bx = blockIdx.x;
    if (bx < nA) gemm_part(ga, bx, stage);
    else         gemm_part(gb, bx - nA, stage);
}

// ---------------- fused epilogue over kq-summed partials ----------------
struct EGR {
    const float* P;     // fp32 partials [ks][256][N]
    const float* x0;    // epilogue input 0
    const float* x1;    // epilogue input 1
    float* y0;          // fp32 state output
    u16* y0b;           // bf16 copy of y0 (EPI3)
    u16* y1b;           // bf16 aux output (T0b/T1b/e2b)
    float* loss;        // loss accumulator (EPI != 2)
    const float* lr;    // inf_lr (EPI1/2)
    int N, nCol, ks;    // nCol = N/64; tiles = 4*nCol
};

template <int EPI>
__device__ void epi_tile(const EGR& g, int tile, float* red8) {
    const int t = threadIdx.x;
    const int w = t >> 6, l = t & 63;
    const int rowBlk = tile / g.nCol, colBlk = tile - rowBlk * g.nCol;
    const int row0 = rowBlk * 64, col0 = colBlk * 64;
    const int row = t >> 3, c8 = (t & 7) * 8;
    const size_t idx = (size_t)(row0 + row) * g.N + col0 + c8;
    const size_t plane = (size_t)256 * g.N;

    // sum ks partials
    const float* p0 = g.P + idx;
    float4x cv[2];
    cv[0] = *(const float4x*)(p0);
    cv[1] = *(const float4x*)(p0 + 4);
    for (int q = 1; q < g.ks; ++q) {
        cv[0] += *(const float4x*)(p0 + (size_t)q * plane);
        cv[1] += *(const float4x*)(p0 + (size_t)q * plane + 4);
    }

    float lr = 0.f;
    if (EPI == 1 || EPI == 2) lr = *g.lr;
    float lsum = 0.f;

    if (EPI == 1) {
        float4x vv[2], mm[2], nv[2]; u16x8 tb;
        vv[0] = *(const float4x*)(g.x0 + idx);       vv[1] = *(const float4x*)(g.x0 + idx + 4);
        mm[0] = *(const float4x*)(g.x1 + col0 + c8); mm[1] = *(const float4x*)(g.x1 + col0 + c8 + 4);
#pragma unroll
        for (int h = 0; h < 2; ++h)
#pragma unroll
            for (int e = 0; e < 4; ++e) {
                float v = vv[h][e], th = tanhf(v), td = 1.f - th * th;
                float d0 = (mm[h][e] - v) - 0.5f * signf_(v) + td * cv[h][e];
                float x = v + lr * d0;
                x = x > 0.f ? x : 0.f;
                nv[h][e] = x;
                tb[h * 4 + e] = f2b(tanhf(x));
                float ne0 = x - mm[h][e];
                lsum += ne0 * ne0;
            }
        *(float4x*)(g.y0 + idx) = nv[0];
        *(float4x*)(g.y0 + idx + 4) = nv[1];
        *(u16x8*)(g.y1b + idx) = tb;
    } else if (EPI == 2) {
        float4x vv[2], ee[2], nv[2]; u16x8 tb;
        vv[0] = *(const float4x*)(g.x0 + idx);     vv[1] = *(const float4x*)(g.x0 + idx + 4);
        ee[0] = *(const float4x*)(g.x1 + idx);     ee[1] = *(const float4x*)(g.x1 + idx + 4);
#pragma unroll
        for (int h = 0; h < 2; ++h)
#pragma unroll
            for (int e = 0; e < 4; ++e) {
                float v = vv[h][e], th = tanhf(v), td = 1.f - th * th;
                float x = v + lr * (-ee[h][e] + td * cv[h][e]);
                x = x > 0.f ? x : 0.f;
                nv[h][e] = x;
                tb[h * 4 + e] = f2b(tanhf(x));
            }
        *(float4x*)(g.y0 + idx) = nv[0];
        *(float4x*)(g.y0 + idx + 4) = nv[1];
        *(u16x8*)(g.y1b + idx) = tb;
    } else if (EPI == 3) {
        float4x vv[2], ne[2]; u16x8 nb;
        vv[0] = *(const float4x*)(g.x0 + idx);     vv[1] = *(const float4x*)(g.x0 + idx + 4);
#pragma unroll
        for (int h = 0; h < 2; ++h)
#pragma unroll
            for (int e = 0; e < 4; ++e) {
                float x = vv[h][e] - cv[h][e];
                ne[h][e] = x;
                nb[h * 4 + e] = f2b(x);
                lsum += x * x;
            }
        *(float4x*)(g.y0 + idx) = ne[0];
        *(float4x*)(g.y0 + idx + 4) = ne[1];
        *(u16x8*)(g.y0b + idx) = nb;
    } else {
        float4x vv[2]; u16x8 nb;
        vv[0] = *(const float4x*)(g.x0 + idx);     vv[1] = *(const float4x*)(g.x0 + idx + 4);
#pragma unroll
        for (int h = 0; h < 2; ++h)
#pragma unroll
            for (int e = 0; e < 4; ++e) {
                float x = vv[h][e] - cv[h][e];
                nb[h * 4 + e] = f2b(x);
                lsum += x * x;
            }
        *(u16x8*)(g.y1b + idx) = nb;
    }

    if (EPI != 2) {
#pragma unroll
        for (int off = 32; off > 0; off >>= 1) lsum += __shfl_down(lsum, off);
        if (l == 0) red8[w] = lsum;
        __syncthreads();
        if (t == 0) {
            float s = 0.f;
#pragma unroll
            for (int q = 0; q < 8; ++q) s += red8[q];
            atomicAdd(g.loss, s * LOSS_SCALE);
        }
    }
}

template <int EPIA, int EPIB>
__global__ __launch_bounds__(512) void pcn_epi(EGR ga, EGR gb, int nA) {
    __shared__ float red8[8];
    int bx = blockIdx.x;
    if (bx < nA) epi_tile<EPIA>(ga, bx, red8);
    else         epi_tile<EPIB>(gb, bx - nA, red8);
}

extern "C" void kernel_launch(void* const* d_in, const int* in_sizes, int n_in,
                              void* d_out, int out_size, void* d_ws, size_t ws_size,
                              hipStream_t stream)
{
    const float* batch_inp = (const float*)d_in[0]; // (256, 8192)
    const float* W0        = (const float*)d_in[1]; // (4096, 2048)
    const float* W1        = (const float*)d_in[2]; // (8192, 4096)
    const float* memory    = (const float*)d_in[3]; // (2048,)
    const float* lr_ptr    = (const float*)d_in[5]; // 0.05
    float* out = (float*)d_out;                     // 8 losses

    const int n0 = 2048, n1 = 4096, n2 = 8192, Bn = 256;

    // ks config: prefer 640-block uniform grids (Ksl=512) if workspace allows
    // CpA = 16 planes (64 MB); otherwise fall back to 384-block config (32 MB).
    const bool big = ws_size >= (size_t)261 * 1024 * 1024;
    const int ks2 = big ? 16 : 8;   // G2 (K=8192)
    const int ks1 = 8;              // G1 (K=4096)
    const int ks4 = big ? 8 : 4;    // G4 (K=4096)
    const int ks3 = 4;              // G3 (K=2048)
    const int planesA = big ? 16 : 8;

    // ---- workspace layout ----
    char* ws = (char*)d_ws;
    auto alloc_f = [&](size_t n) { float* p = (float*)ws; ws += n * 4; return p; };
    auto alloc_b = [&](size_t n) { u16* p = (u16*)ws; ws += n * 2; return p; };

    float* v0  = alloc_f((size_t)Bn * n0);
    float* v1  = alloc_f((size_t)Bn * n1);
    float* e1  = alloc_f((size_t)Bn * n1);
    u16*   e1b = alloc_b((size_t)Bn * n1);
    u16*   e2b = alloc_b((size_t)Bn * n2);
    u16*   T0b = alloc_b((size_t)Bn * n0);
    u16*   T1b = alloc_b((size_t)Bn * n1);
    u16*   W0b  = alloc_b((size_t)n1 * n0);   // (n1, n0) = W0 cast
    u16*   W0Tb = alloc_b((size_t)n0 * n1);   // (n0, n1) = W0^T cast
    u16*   W1b  = alloc_b((size_t)n2 * n1);   // (n2, n1) = W1 cast
    u16*   W1Tb = alloc_b((size_t)n1 * n2);   // (n1, n2) = W1^T cast
    float* tm = alloc_f(n0);
    float* r1 = alloc_f(n1);
    float* t1 = alloc_f(n1);
    float* r2 = alloc_f(n2);
    // fp32 partial buffers (aliased across phases):
    //   CpA: planesA x 256 x 4096 fp32 (= big ? 64 : 32 MB); covers G4's
    //        ks4 x 256 x 8192 exactly (planesA*n1 == ks4*n2 elements/row-blk)
    //   CpB: 8 x 256 x 2048 fp32 (16 MB); covers G3's 4 x 256 x 4096
    float* CpA = alloc_f((size_t)planesA * Bn * n1);
    float* CpB = alloc_f((size_t)8 * Bn * n0);

    // ---- one-time init ----
    k_zero<<<1, 32, 0, stream>>>(out, 8);
    k_cast_both<<<dim3(n0 / 64, n1 / 64), dim3(64, 4), 0, stream>>>(W0, W0b, W0Tb, n1, n0);
    k_cast_both<<<dim3(n1 / 64, n2 / 64), dim3(64, 4), 0, stream>>>(W1, W1b, W1Tb, n2, n1);
    k_fill_v0<<<(Bn * n0) / 256, 256, 0, stream>>>(v0, memory, Bn * n0, n0 - 1);
    k_tanh<<<n0 / 256, 256, 0, stream>>>(tm, memory, n0);
    k_rowdot<<<n1, 256, 0, stream>>>(tm, W0, r1, n0);        // r1 = tanh(mem) @ W0^T
    k_tanh<<<n1 / 256, 256, 0, stream>>>(t1, r1, n1);
    k_bcast_v1_e1<<<(Bn * n1) / 256, 256, 0, stream>>>(v1, e1, e1b, r1, Bn * n1, n1 - 1);
    k_rowdot<<<n2, 256, 0, stream>>>(t1, W1, r2, n1);        // r2 = tanh(r1) @ W1^T
    k_e2_init<<<(Bn * n2) / 256, 256, 0, stream>>>(e2b, batch_inp, r2, Bn * n2, n2 - 1);

    // ---- 8 inference iterations ----
    for (int it = 0; it < 8; ++it) {
        float* loss = out + it;

        // gemm1: G2p = e2@W1 partials || G1p = e1@W0 partials
        GGR g2{e2b, W1Tb, CpA, n1, n2, n1 / 128, ks2};
        GGR g1{e1b, W0Tb, CpB, n0, n1, n0 / 128, ks1};
        pcn_gemm<<<(n1 / 128) * ks2 + (n0 / 128) * ks1, 256, 0, stream>>>(
            g2, g1, (n1 / 128) * ks2);

        // epi1: EPI2 over G2 (256 tiles) || EPI1 over G1 (128 tiles)
        EGR e2g{CpA, v1, e1, v1, nullptr, T1b, nullptr, lr_ptr, n1, n1 / 64, ks2};
        EGR e1g{CpB, v0, memory, v0, nullptr, T0b, loss, lr_ptr, n0, n0 / 64, ks1};
        pcn_epi<2, 1><<<4 * (n1 / 64) + 4 * (n0 / 64), 512, 0, stream>>>(
            e2g, e1g, 4 * (n1 / 64));

        // gemm2: G4p = T1@W1^T partials || G3p = T0@W0^T partials
        GGR g4{T1b, W1b, CpA, n2, n1, n2 / 128, ks4};
        GGR g3{T0b, W0b, CpB, n1, n0, n1 / 128, ks3};
        pcn_gemm<<<(n2 / 128) * ks4 + (n1 / 128) * ks3, 256, 0, stream>>>(
            g4, g3, (n2 / 128) * ks4);

        // epi2: EPI4 over G4 (512 tiles) || EPI3 over G3 (256 tiles)
        EGR e4g{CpA, batch_inp, nullptr, nullptr, nullptr, e2b, loss, nullptr, n2, n2 / 64, ks4};
        EGR e3g{CpB, v1, nullptr, e1, e1b, nullptr, loss, nullptr, n1, n1 / 64, ks3};
        pcn_epi<4, 3><<<4 * (n2 / 64) + 4 * (n1 / 64), 512, 0, stream>>>(
            e4g, e3g, 4 * (n2 / 64));
    }
}